// Round 1
// 207.557 us; speedup vs baseline: 1.0204x; 1.0204x over previous
//
#include <hip/hip_runtime.h>
#include <math.h>

#define B_ 8
#define N_ 1024
#define D_ 512
#define H_ 4
#define ND (N_ * D_)      // 524288
#define DD (D_ * D_)      // 262144
#define NN (N_ * N_)      // 1048576

typedef _Float16 f16;
typedef f16 f16x8 __attribute__((ext_vector_type(8)));
typedef float f32x4 __attribute__((ext_vector_type(4)));

typedef __attribute__((address_space(3))) void lds_void;
typedef __attribute__((address_space(1))) void g_void;

// =====================================================================
// R8-proven paired-tile core: TWO stacked 128x128 C-tiles sharing the
// staged B tile. NPROD=1: 3 tiles staged -> 32 MFMA/wave per K-step.
// EPI: f16(acc * scale)  (scale=1.0f folds away for g1/g4).
// =====================================================================
template<int NPROD, int LDA, int LDB, int LDC, int KTOT>
__device__ __forceinline__ void pair_core(
    const f16* __restrict__ A, const f16* __restrict__ B0,
    const f16* __restrict__ B1, f16* __restrict__ Ch, float scale,
    int n0, int c0)
{
    __shared__ f16 sA[256 * 32];
    __shared__ f16 sB0[128 * 32];
    __shared__ f16 sB1[(NPROD == 2) ? 128 * 32 : 64];

    const int t = threadIdx.x;
    const int w = t >> 6;
    const int l = t & 63;
    const int lrow = l >> 2;
    const int lch  = l & 3;
    const int wr = w >> 1, wc = w & 1;
    const int fr = l & 15;
    const int fq = l >> 4;

    f32x4 acc0[4][4] = {};
    f32x4 acc1[4][4] = {};

    for (int k0 = 0; k0 < KTOT; k0 += 32) {
#pragma unroll
        for (int i = 0; i < 4; ++i) {
            const int rb  = w * 4 + i;
            const int row = rb * 16 + lrow;
            const f16* ga = A + (size_t)(n0 + row) * LDA + k0 + lch * 8;
            __builtin_amdgcn_global_load_lds((g_void*)ga, (lds_void*)(sA + rb * 512), 16, 0, 0);
        }
#pragma unroll
        for (int i = 0; i < 2; ++i) {
            const int rb  = w * 2 + i;
            const int row = rb * 16 + lrow;
            const f16* gb0 = B0 + (size_t)(c0 + row) * LDB + k0 + lch * 8;
            __builtin_amdgcn_global_load_lds((g_void*)gb0, (lds_void*)(sB0 + rb * 512), 16, 0, 0);
            if constexpr (NPROD == 2) {
                const f16* gb1 = B1 + (size_t)(c0 + row) * LDB + k0 + lch * 8;
                __builtin_amdgcn_global_load_lds((g_void*)gb1, (lds_void*)(sB1 + rb * 512), 16, 0, 0);
            }
        }
        __syncthreads();

        f16x8 a0[4], a1[4], b0[4], b1[4];
#pragma unroll
        for (int i = 0; i < 4; ++i) {
            a0[i] = *(const f16x8*)(sA + (wr * 64 + i * 16 + fr) * 32 + fq * 8);
            a1[i] = *(const f16x8*)(sA + (128 * 32) + (wr * 64 + i * 16 + fr) * 32 + fq * 8);
            b0[i] = *(const f16x8*)(sB0 + (wc * 64 + i * 16 + fr) * 32 + fq * 8);
            if constexpr (NPROD == 2)
                b1[i] = *(const f16x8*)(sB1 + (wc * 64 + i * 16 + fr) * 32 + fq * 8);
        }

#pragma unroll
        for (int i = 0; i < 4; ++i)
#pragma unroll
            for (int j = 0; j < 4; ++j) {
                acc0[i][j] = __builtin_amdgcn_mfma_f32_16x16x32_f16(a0[i], b0[j], acc0[i][j], 0, 0, 0);
                acc1[i][j] = __builtin_amdgcn_mfma_f32_16x16x32_f16(a1[i], b0[j], acc1[i][j], 0, 0, 0);
                if constexpr (NPROD == 2) {
                    acc0[i][j] = __builtin_amdgcn_mfma_f32_16x16x32_f16(a0[i], b1[j], acc0[i][j], 0, 0, 0);
                    acc1[i][j] = __builtin_amdgcn_mfma_f32_16x16x32_f16(a1[i], b1[j], acc1[i][j], 0, 0, 0);
                }
            }
        __syncthreads();
    }

#pragma unroll
    for (int i = 0; i < 4; ++i)
#pragma unroll
        for (int j = 0; j < 4; ++j)
#pragma unroll
            for (int r = 0; r < 4; ++r) {
                const int row = n0 + wr * 64 + i * 16 + fq * 4 + r;
                const int col = c0 + wc * 64 + j * 16 + fr;
                Ch[(size_t)row * LDC + col] = (f16)(acc0[i][j][r] * scale);
                Ch[(size_t)(row + 128) * LDC + col] = (f16)(acc1[i][j][r] * scale);
            }
}

// GEMM1: Yh[z] = f16( x[b] @ Wh[h] ), z=b*4+h. xcd=b. 512 blocks, paired,
// SINGLE product (Wl dropped: W-f16 rounding adds ~3.2e-3 logit noise,
// one of four equal terms — predicted absmax ~0.038 < 0.0494).
__global__ __launch_bounds__(256, 2) void k_g1(
    const f16* __restrict__ xfh, const f16* __restrict__ wTh,
    f16* __restrict__ Yh)
{
    const int i = blockIdx.x;
    const int b = i & 7;
    const int li = i >> 3;            // 0..63
    const int h = li >> 4;
    const int n0 = ((li >> 2) & 3) * 256;
    const int e0 = (li & 3) * 128;
    const int z = b * 4 + h;
    pair_core<1, D_, D_, D_, D_>(
        xfh + (size_t)b * ND,
        wTh + (size_t)h * DD, nullptr,
        Yh + (size_t)z * ND, 1.0f, n0, e0);
}

// GEMM2: S[z] = f16( Yh[z] @ xh[b]^T * scale ). xcd=b. Now PAIRED
// (256x128 C-tile, two Y row-tiles share the staged x tile): 32 MFMA
// per 2-barrier K-step vs single_core's 16 — same structure g4 uses,
// which never shows in top-5 at identical FLOPs. 1024 blocks.
__global__ __launch_bounds__(256, 2) void k_g2(
    const f16* __restrict__ Yh, const f16* __restrict__ xfh,
    f16* __restrict__ S)
{
    const int i = blockIdx.x;
    const int b = i & 7;
    const int li = i >> 3;           // 0..127
    const int h = li >> 5;           // 0..3
    const int n0 = ((li >> 3) & 3) * 256;
    const int m0 = (li & 7) * 128;
    const int z = b * 4 + h;
    pair_core<1, D_, D_, N_, D_>(
        Yh + (size_t)z * ND,
        xfh + (size_t)b * ND, nullptr,
        S + (size_t)z * NN, 0.044194173824159216f, n0, m0);
}

// GEMM4 split-K by head: part[z] = f16( P[z] @ xT[b]^T ). xcd=b. 512 blocks, paired.
__global__ __launch_bounds__(256, 2) void k_g4(
    const f16* __restrict__ P, const f16* __restrict__ xT,
    f16* __restrict__ part)
{
    const int i = blockIdx.x;
    const int b = i & 7;
    const int li = i >> 3;            // 0..63
    const int h = li >> 4;
    const int n0 = ((li >> 2) & 3) * 256;
    const int d0 = (li & 3) * 128;
    const int z = b * 4 + h;
    pair_core<1, N_, N_, D_, N_>(
        P + (size_t)z * NN,
        xT + (size_t)b * ND, nullptr,
        part + (size_t)z * ND, 1.0f, n0, d0);
}

// Reduce: out[b] = 0.25 * sum_h part[b*4+h]   (f16 partials, 8 elems/thread)
__global__ __launch_bounds__(256) void k_reduce(
    const f16* __restrict__ part, float* __restrict__ out)
{
    const int i = blockIdx.x * 256 + threadIdx.x;
    const int b = i / (ND / 8);
    const int r = i - b * (ND / 8);
    const f16x8* p = (const f16x8*)part;
    f16x8 a0 = p[(size_t)(b * 4 + 0) * (ND / 8) + r];
    f16x8 a1 = p[(size_t)(b * 4 + 1) * (ND / 8) + r];
    f16x8 a2 = p[(size_t)(b * 4 + 2) * (ND / 8) + r];
    f16x8 a3 = p[(size_t)(b * 4 + 3) * (ND / 8) + r];
    float4 o0, o1;
    float* o = (float*)&o0;
#pragma unroll
    for (int k = 0; k < 4; ++k)
        o[k] = 0.25f * ((float)a0[k] + (float)a1[k] + (float)a2[k] + (float)a3[k]);
    o = (float*)&o1;
#pragma unroll
    for (int k = 0; k < 4; ++k)
        o[k] = 0.25f * ((float)a0[k+4] + (float)a1[k+4] + (float)a2[k+4] + (float)a3[k+4]);
    ((float4*)out)[(size_t)i * 2]     = o0;
    ((float4*)out)[(size_t)i * 2 + 1] = o1;
}

// Merged decomp: z<8 -> x-batch z (f16 hi + transposed hi); z>=8 -> W head
// z-8 (hi only + transpose). Grid (8,16,12); W part uses y<8 only.
__global__ __launch_bounds__(256) void decomp_xw(
    const float* __restrict__ x, const float* __restrict__ W,
    f16* __restrict__ xfh, f16* __restrict__ xT, f16* __restrict__ wTh)
{
    __shared__ f16 tile[64][65];
    __shared__ float tw[64][65];
    const int t = threadIdx.x;
    const int z = blockIdx.z;
    if (z < 8) {
        const int b = z, n0 = blockIdx.y * 64, d0 = blockIdx.x * 64;
        const float* xb = x + (size_t)b * ND;
#pragma unroll
        for (int p = 0; p < 16; ++p) {
            const int idx = t + p * 256;
            const int r = idx >> 6, c = idx & 63;
            const float v = xb[(size_t)(n0 + r) * D_ + d0 + c];
            const f16 h = (f16)v;
            xfh[(size_t)b * ND + (size_t)(n0 + r) * D_ + d0 + c] = h;
            tile[r][c] = h;
        }
        __syncthreads();
#pragma unroll
        for (int p = 0; p < 16; ++p) {
            const int idx = t + p * 256;
            const int r = idx >> 6, c = idx & 63;
            xT[(size_t)b * ND + (size_t)(d0 + r) * N_ + n0 + c] = tile[c][r];
        }
    } else {
        if (blockIdx.y >= 8) return;
        const int h = z - 8, d0 = blockIdx.y * 64, e0 = blockIdx.x * 64;
        const float* Wh = W + (size_t)h * DD;
#pragma unroll
        for (int p = 0; p < 16; ++p) {
            const int idx = t + p * 256;
            const int r = idx >> 6, c = idx & 63;
            tw[r][c] = Wh[(size_t)(d0 + r) * D_ + e0 + c];
        }
        __syncthreads();
#pragma unroll
        for (int p = 0; p < 16; ++p) {
            const int idx = t + p * 256;
            const int r = idx >> 6, c = idx & 63;
            wTh[(size_t)h * DD + (size_t)(e0 + r) * D_ + d0 + c] = (f16)tw[c][r];
        }
    }
}

// Barrier-free softmax, XCD-aligned: block i -> b = i&7 (same placement as
// the g2 blocks that wrote S[b's z-range]) so S reads hit the local L2.
// One wave per row, 4 rows/block. 8192 blocks.
__global__ __launch_bounds__(256) void softmax_wave(
    const f16* __restrict__ S, f16* __restrict__ P)
{
    const int wave = threadIdx.x >> 6;
    const int l = threadIdx.x & 63;
    const int i = blockIdx.x;
    const int b = i & 7;
    const int li = i >> 3;            // 0..1023
    const int h = li >> 8;            // 0..3
    const int rg = li & 255;          // 0..255 row-group (4 rows)
    const size_t row = (size_t)(b * 4 + h) * N_ + rg * 4 + wave;

    const f16x8* p = (const f16x8*)(S + row * N_);
    f16x8 v0 = p[l * 2], v1 = p[l * 2 + 1];

    float f[16];
#pragma unroll
    for (int k = 0; k < 8; ++k) { f[k] = (float)v0[k]; f[k + 8] = (float)v1[k]; }

    float m = f[0];
#pragma unroll
    for (int k = 1; k < 16; ++k) m = fmaxf(m, f[k]);
#pragma unroll
    for (int o = 32; o > 0; o >>= 1) m = fmaxf(m, __shfl_xor(m, o));

    float s = 0.f;
#pragma unroll
    for (int k = 0; k < 16; ++k) { f[k] = __expf(f[k] - m); s += f[k]; }
#pragma unroll
    for (int o = 32; o > 0; o >>= 1) s += __shfl_xor(s, o);

    const float inv = 1.0f / s;
    f16x8 o0, o1;
#pragma unroll
    for (int k = 0; k < 8; ++k) {
        o0[k] = (f16)(f[k] * inv);
        o1[k] = (f16)(f[k + 8] * inv);
    }
    f16x8* q = (f16x8*)(P + row * N_);
    q[l * 2] = o0;
    q[l * 2 + 1] = o1;
}

extern "C" void kernel_launch(void* const* d_in, const int* in_sizes, int n_in,
                              void* d_out, int out_size, void* d_ws, size_t ws_size,
                              hipStream_t stream) {
    const float* x = (const float*)d_in[0];   // [8,1024,512]
    const float* W = (const float*)d_in[1];   // [4,512,512]
    float* out = (float*)d_out;               // [8,1024,512]

    // workspace layout (proven footprint)
    char* ws = (char*)d_ws;
    const size_t MB = 1024 * 1024;
    f16*   xfh = (f16*)(ws + 0 * MB);     // 8 MiB
    f16*   xT  = (f16*)(ws + 8 * MB);     // 8 MiB
    f16*   wTh = (f16*)(ws + 16 * MB);    // 2 MiB
    f16*   Yh  = (f16*)(ws + 20 * MB);    // 32 MiB (full batch, 32 z)
    f16*   S   = (f16*)(ws + 52 * MB);    // 64 MiB (full batch, f16)
    f16*   P   = (f16*)(ws + 116 * MB);   // 64 MiB (full batch, f16)
    f16*   part = S;                      // g4 partials (32 MiB) reuse S

    decomp_xw<<<dim3(8, 16, 12), 256, 0, stream>>>(x, W, xfh, xT, wTh);

    k_g1<<<dim3(512), 256, 0, stream>>>(xfh, wTh, Yh);
    k_g2<<<dim3(1024), 256, 0, stream>>>(Yh, xfh, S);
    softmax_wave<<<dim3(B_ * H_ * N_ / 4), 256, 0, stream>>>(S, P);
    k_g4<<<dim3(512), 256, 0, stream>>>(P, xT, part);
    k_reduce<<<dim3((B_ * ND / 8) / 256), 256, 0, stream>>>(part, out);
}

// Round 2
// 207.065 us; speedup vs baseline: 1.0228x; 1.0024x over previous
//
#include <hip/hip_runtime.h>
#include <math.h>

#define B_ 8
#define N_ 1024
#define D_ 512
#define H_ 4
#define ND (N_ * D_)      // 524288
#define DD (D_ * D_)      // 262144
#define NN (N_ * N_)      // 1048576

typedef _Float16 f16;
typedef f16 f16x8 __attribute__((ext_vector_type(8)));
typedef float f32x4 __attribute__((ext_vector_type(4)));

typedef __attribute__((address_space(3))) void lds_void;
typedef __attribute__((address_space(1))) void g_void;

// =====================================================================
// Paired-tile core with 2-phase double-buffered K-loop (T3 minimum
// recipe): issue next K-step's global_load_lds BEFORE current step's
// ds_read+MFMA; ONE barrier per K-step. Buffers are DISTINCT named
// __shared__ arrays so alias analysis doesn't serialize the prefetch.
// TWO stacked 128x128 C-tiles share the staged B tile: 32 MFMA/wave
// per K-step. EPI: f16(acc * scale).
// =====================================================================

#define STAGE_P(SA_, SB_, K0_)                                              \
    {                                                                        \
        _Pragma("unroll")                                                    \
        for (int i_ = 0; i_ < 4; ++i_) {                                     \
            const int rb_  = w * 4 + i_;                                     \
            const int row_ = rb_ * 16 + lrow;                                \
            const f16* ga_ = A + (size_t)(n0 + row_) * LDA + (K0_) + lch * 8;\
            __builtin_amdgcn_global_load_lds((g_void*)ga_,                   \
                (lds_void*)(SA_ + rb_ * 512), 16, 0, 0);                     \
        }                                                                    \
        _Pragma("unroll")                                                    \
        for (int i_ = 0; i_ < 2; ++i_) {                                     \
            const int rb_  = w * 2 + i_;                                     \
            const int row_ = rb_ * 16 + lrow;                                \
            const f16* gb_ = B0 + (size_t)(c0 + row_) * LDB + (K0_) + lch * 8;\
            __builtin_amdgcn_global_load_lds((g_void*)gb_,                   \
                (lds_void*)(SB_ + rb_ * 512), 16, 0, 0);                     \
        }                                                                    \
    }

#define COMPUTE_P(SA_, SB_)                                                  \
    {                                                                        \
        f16x8 a0_[4], a1_[4], b0_[4];                                        \
        _Pragma("unroll")                                                    \
        for (int i_ = 0; i_ < 4; ++i_) {                                     \
            a0_[i_] = *(const f16x8*)(SA_ + (wr * 64 + i_ * 16 + fr) * 32 + fq * 8); \
            a1_[i_] = *(const f16x8*)(SA_ + (128 * 32) + (wr * 64 + i_ * 16 + fr) * 32 + fq * 8); \
            b0_[i_] = *(const f16x8*)(SB_ + (wc * 64 + i_ * 16 + fr) * 32 + fq * 8); \
        }                                                                    \
        _Pragma("unroll")                                                    \
        for (int i_ = 0; i_ < 4; ++i_)                                       \
            _Pragma("unroll")                                                \
            for (int j_ = 0; j_ < 4; ++j_) {                                 \
                acc0[i_][j_] = __builtin_amdgcn_mfma_f32_16x16x32_f16(a0_[i_], b0_[j_], acc0[i_][j_], 0, 0, 0); \
                acc1[i_][j_] = __builtin_amdgcn_mfma_f32_16x16x32_f16(a1_[i_], b0_[j_], acc1[i_][j_], 0, 0, 0); \
            }                                                                \
    }

template<int LDA, int LDB, int LDC, int KTOT>
__device__ __forceinline__ void pair_core(
    const f16* __restrict__ A, const f16* __restrict__ B0,
    f16* __restrict__ Ch, float scale, int n0, int c0)
{
    // distinct named buffers: provable non-aliasing for the prefetch
    __shared__ f16 sAa[256 * 32];
    __shared__ f16 sAb[256 * 32];
    __shared__ f16 sBa[128 * 32];
    __shared__ f16 sBb[128 * 32];

    const int t = threadIdx.x;
    const int w = t >> 6;
    const int l = t & 63;
    const int lrow = l >> 2;
    const int lch  = l & 3;
    const int wr = w >> 1, wc = w & 1;
    const int fr = l & 15;
    const int fq = l >> 4;

    f32x4 acc0[4][4] = {};
    f32x4 acc1[4][4] = {};

    // prologue: stage step 0 into buffer a
    STAGE_P(sAa, sBa, 0);
    __syncthreads();

    // steady state: 2 K-steps per iteration, buffers alternate a/b.
    // stage(next) is issued BEFORE compute(current); the single
    // __syncthreads() per K-step drains vmcnt AFTER the MFMAs.
#pragma unroll
    for (int it = 0; it < KTOT / 64; ++it) {
        const int k0 = it * 64;
        STAGE_P(sAb, sBb, k0 + 32);      // always valid: k0+32 <= KTOT-32
        COMPUTE_P(sAa, sBa);
        __syncthreads();
        if (k0 + 64 < KTOT) STAGE_P(sAa, sBa, k0 + 64);
        COMPUTE_P(sAb, sBb);
        __syncthreads();
    }

#pragma unroll
    for (int i = 0; i < 4; ++i)
#pragma unroll
        for (int j = 0; j < 4; ++j)
#pragma unroll
            for (int r = 0; r < 4; ++r) {
                const int row = n0 + wr * 64 + i * 16 + fq * 4 + r;
                const int col = c0 + wc * 64 + j * 16 + fr;
                Ch[(size_t)row * LDC + col] = (f16)(acc0[i][j][r] * scale);
                Ch[(size_t)(row + 128) * LDC + col] = (f16)(acc1[i][j][r] * scale);
            }
}

// GEMM1: Yh[z] = f16( x[b] @ Wh[h] ), z=b*4+h. xcd=b. 512 blocks, paired,
// SINGLE product (Wl dropped: W-f16 rounding adds ~3.2e-3 logit noise,
// one of four equal terms — measured absmax 0.0332 < 0.0494).
__global__ __launch_bounds__(256, 2) void k_g1(
    const f16* __restrict__ xfh, const f16* __restrict__ wTh,
    f16* __restrict__ Yh)
{
    const int i = blockIdx.x;
    const int b = i & 7;
    const int li = i >> 3;            // 0..63
    const int h = li >> 4;
    const int n0 = ((li >> 2) & 3) * 256;
    const int e0 = (li & 3) * 128;
    const int z = b * 4 + h;
    pair_core<D_, D_, D_, D_>(
        xfh + (size_t)b * ND,
        wTh + (size_t)h * DD,
        Yh + (size_t)z * ND, 1.0f, n0, e0);
}

// GEMM2: S[z] = f16( Yh[z] @ xh[b]^T * scale ). xcd=b. 1024 blocks, paired.
__global__ __launch_bounds__(256, 2) void k_g2(
    const f16* __restrict__ Yh, const f16* __restrict__ xfh,
    f16* __restrict__ S)
{
    const int i = blockIdx.x;
    const int b = i & 7;
    const int li = i >> 3;           // 0..127
    const int h = li >> 5;           // 0..3
    const int n0 = ((li >> 3) & 3) * 256;
    const int m0 = (li & 7) * 128;
    const int z = b * 4 + h;
    pair_core<D_, D_, N_, D_>(
        Yh + (size_t)z * ND,
        xfh + (size_t)b * ND,
        S + (size_t)z * NN, 0.044194173824159216f, n0, m0);
}

// GEMM4 split-K by head: part[z] = f16( P[z] @ xT[b]^T ). xcd=b. 512 blocks, paired.
__global__ __launch_bounds__(256, 2) void k_g4(
    const f16* __restrict__ P, const f16* __restrict__ xT,
    f16* __restrict__ part)
{
    const int i = blockIdx.x;
    const int b = i & 7;
    const int li = i >> 3;            // 0..63
    const int h = li >> 4;
    const int n0 = ((li >> 2) & 3) * 256;
    const int d0 = (li & 3) * 128;
    const int z = b * 4 + h;
    pair_core<N_, N_, D_, N_>(
        P + (size_t)z * NN,
        xT + (size_t)b * ND,
        part + (size_t)z * ND, 1.0f, n0, d0);
}

// Reduce: out[b] = 0.25 * sum_h part[b*4+h]   (f16 partials, 8 elems/thread)
__global__ __launch_bounds__(256) void k_reduce(
    const f16* __restrict__ part, float* __restrict__ out)
{
    const int i = blockIdx.x * 256 + threadIdx.x;
    const int b = i / (ND / 8);
    const int r = i - b * (ND / 8);
    const f16x8* p = (const f16x8*)part;
    f16x8 a0 = p[(size_t)(b * 4 + 0) * (ND / 8) + r];
    f16x8 a1 = p[(size_t)(b * 4 + 1) * (ND / 8) + r];
    f16x8 a2 = p[(size_t)(b * 4 + 2) * (ND / 8) + r];
    f16x8 a3 = p[(size_t)(b * 4 + 3) * (ND / 8) + r];
    float4 o0, o1;
    float* o = (float*)&o0;
#pragma unroll
    for (int k = 0; k < 4; ++k)
        o[k] = 0.25f * ((float)a0[k] + (float)a1[k] + (float)a2[k] + (float)a3[k]);
    o = (float*)&o1;
#pragma unroll
    for (int k = 0; k < 4; ++k)
        o[k] = 0.25f * ((float)a0[k+4] + (float)a1[k+4] + (float)a2[k+4] + (float)a3[k+4]);
    ((float4*)out)[(size_t)i * 2]     = o0;
    ((float4*)out)[(size_t)i * 2 + 1] = o1;
}

// Merged decomp: z<8 -> x-batch z (f16 hi + transposed hi); z>=8 -> W head
// z-8 (hi only + transpose). Grid (8,16,12); W part uses y<8 only.
__global__ __launch_bounds__(256) void decomp_xw(
    const float* __restrict__ x, const float* __restrict__ W,
    f16* __restrict__ xfh, f16* __restrict__ xT, f16* __restrict__ wTh)
{
    __shared__ f16 tile[64][65];
    __shared__ float tw[64][65];
    const int t = threadIdx.x;
    const int z = blockIdx.z;
    if (z < 8) {
        const int b = z, n0 = blockIdx.y * 64, d0 = blockIdx.x * 64;
        const float* xb = x + (size_t)b * ND;
#pragma unroll
        for (int p = 0; p < 16; ++p) {
            const int idx = t + p * 256;
            const int r = idx >> 6, c = idx & 63;
            const float v = xb[(size_t)(n0 + r) * D_ + d0 + c];
            const f16 h = (f16)v;
            xfh[(size_t)b * ND + (size_t)(n0 + r) * D_ + d0 + c] = h;
            tile[r][c] = h;
        }
        __syncthreads();
#pragma unroll
        for (int p = 0; p < 16; ++p) {
            const int idx = t + p * 256;
            const int r = idx >> 6, c = idx & 63;
            xT[(size_t)b * ND + (size_t)(d0 + r) * N_ + n0 + c] = tile[c][r];
        }
    } else {
        if (blockIdx.y >= 8) return;
        const int h = z - 8, d0 = blockIdx.y * 64, e0 = blockIdx.x * 64;
        const float* Wh = W + (size_t)h * DD;
#pragma unroll
        for (int p = 0; p < 16; ++p) {
            const int idx = t + p * 256;
            const int r = idx >> 6, c = idx & 63;
            tw[r][c] = Wh[(size_t)(d0 + r) * D_ + e0 + c];
        }
        __syncthreads();
#pragma unroll
        for (int p = 0; p < 16; ++p) {
            const int idx = t + p * 256;
            const int r = idx >> 6, c = idx & 63;
            wTh[(size_t)h * DD + (size_t)(e0 + r) * D_ + d0 + c] = (f16)tw[c][r];
        }
    }
}

// Barrier-free softmax, XCD-aligned: block i -> b = i&7 (same placement as
// the g2 blocks that wrote S[b's z-range]) so S reads hit the local L2.
// One wave per row, 4 rows/block. 8192 blocks.
__global__ __launch_bounds__(256) void softmax_wave(
    const f16* __restrict__ S, f16* __restrict__ P)
{
    const int wave = threadIdx.x >> 6;
    const int l = threadIdx.x & 63;
    const int i = blockIdx.x;
    const int b = i & 7;
    const int li = i >> 3;            // 0..1023
    const int h = li >> 8;            // 0..3
    const int rg = li & 255;          // 0..255 row-group (4 rows)
    const size_t row = (size_t)(b * 4 + h) * N_ + rg * 4 + wave;

    const f16x8* p = (const f16x8*)(S + row * N_);
    f16x8 v0 = p[l * 2], v1 = p[l * 2 + 1];

    float f[16];
#pragma unroll
    for (int k = 0; k < 8; ++k) { f[k] = (float)v0[k]; f[k + 8] = (float)v1[k]; }

    float m = f[0];
#pragma unroll
    for (int k = 1; k < 16; ++k) m = fmaxf(m, f[k]);
#pragma unroll
    for (int o = 32; o > 0; o >>= 1) m = fmaxf(m, __shfl_xor(m, o));

    float s = 0.f;
#pragma unroll
    for (int k = 0; k < 16; ++k) { f[k] = __expf(f[k] - m); s += f[k]; }
#pragma unroll
    for (int o = 32; o > 0; o >>= 1) s += __shfl_xor(s, o);

    const float inv = 1.0f / s;
    f16x8 o0, o1;
#pragma unroll
    for (int k = 0; k < 8; ++k) {
        o0[k] = (f16)(f[k] * inv);
        o1[k] = (f16)(f[k + 8] * inv);
    }
    f16x8* q = (f16x8*)(P + row * N_);
    q[l * 2] = o0;
    q[l * 2 + 1] = o1;
}

extern "C" void kernel_launch(void* const* d_in, const int* in_sizes, int n_in,
                              void* d_out, int out_size, void* d_ws, size_t ws_size,
                              hipStream_t stream) {
    const float* x = (const float*)d_in[0];   // [8,1024,512]
    const float* W = (const float*)d_in[1];   // [4,512,512]
    float* out = (float*)d_out;               // [8,1024,512]

    // workspace layout (proven footprint)
    char* ws = (char*)d_ws;
    const size_t MB = 1024 * 1024;
    f16*   xfh = (f16*)(ws + 0 * MB);     // 8 MiB
    f16*   xT  = (f16*)(ws + 8 * MB);     // 8 MiB
    f16*   wTh = (f16*)(ws + 16 * MB);    // 2 MiB
    f16*   Yh  = (f16*)(ws + 20 * MB);    // 32 MiB (full batch, 32 z)
    f16*   S   = (f16*)(ws + 52 * MB);    // 64 MiB (full batch, f16)
    f16*   P   = (f16*)(ws + 116 * MB);   // 64 MiB (full batch, f16)
    f16*   part = S;                      // g4 partials (32 MiB) reuse S

    decomp_xw<<<dim3(8, 16, 12), 256, 0, stream>>>(x, W, xfh, xT, wTh);

    k_g1<<<dim3(512), 256, 0, stream>>>(xfh, wTh, Yh);
    k_g2<<<dim3(1024), 256, 0, stream>>>(Yh, xfh, S);
    softmax_wave<<<dim3(B_ * H_ * N_ / 4), 256, 0, stream>>>(S, P);
    k_g4<<<dim3(512), 256, 0, stream>>>(P, xT, part);
    k_reduce<<<dim3((B_ * ND / 8) / 256), 256, 0, stream>>>(part, out);
}